// Round 1
// baseline (727.365 us; speedup 1.0000x reference)
//
#include <hip/hip_runtime.h>

typedef __attribute__((ext_vector_type(8))) short s16x8;
typedef __attribute__((ext_vector_type(4))) float f32x4;

#define B_    2
#define S_    2048
#define DIM_  2048
#define H_    16
#define KVH_  4
#define HD_   128
#define NQKV  3072

static __device__ __forceinline__ unsigned short f2bf(float f) {
  unsigned int u = __float_as_uint(f);
  u += 0x7fff + ((u >> 16) & 1);
  return (unsigned short)(u >> 16);
}
static __device__ __forceinline__ float bf2f(unsigned short h) {
  return __uint_as_float(((unsigned int)h) << 16);
}

// ---------------- cast f32 -> bf16 (vectorized) ----------------
__global__ __launch_bounds__(256) void cast_f32_bf16(const float* __restrict__ src,
                                                     unsigned short* __restrict__ dst, int n) {
  int i = (blockIdx.x * 256 + threadIdx.x) * 8;
  if (i >= n) return;
  float4 a = *(const float4*)(src + i);
  float4 b = *(const float4*)(src + i + 4);
  uint4 o;
  o.x = (unsigned)f2bf(a.x) | ((unsigned)f2bf(a.y) << 16);
  o.y = (unsigned)f2bf(a.z) | ((unsigned)f2bf(a.w) << 16);
  o.z = (unsigned)f2bf(b.x) | ((unsigned)f2bf(b.y) << 16);
  o.w = (unsigned)f2bf(b.z) | ((unsigned)f2bf(b.w) << 16);
  *(uint4*)(dst + i) = o;
}

// ---------------- m97-style GEMM: C[M,N] = A[M,K] * B[N,K]^T ----------------
// 128x128 tile, BK=32, 4 waves (2x2), each wave 64x64 = 4x4 frags of 16x16x32.
template <bool BF16OUT>
__global__ __launch_bounds__(256) void gemm_bt(const unsigned short* __restrict__ A,
                                               const unsigned short* __restrict__ Bw,
                                               void* __restrict__ Cp, int N, int K) {
  __shared__ __align__(16) unsigned short As[128 * 32];
  __shared__ __align__(16) unsigned short Bs[128 * 32];
  const int tid = threadIdx.x;
  const int n0 = blockIdx.x * 128, m0 = blockIdx.y * 128;
  const int w = tid >> 6, l = tid & 63;
  const int wr = w >> 1, wc = w & 1;
  const int lo = l & 15, hi = l >> 4;
  f32x4 acc[4][4] = {};
  const int KT = K >> 5;
  for (int kt = 0; kt < KT; ++kt) {
    const int k0 = kt << 5;
    __syncthreads();  // protect LDS: all waves finished reading previous tile
#pragma unroll
    for (int c = 0; c < 2; ++c) {
      int idx = tid + c * 256;
      int row = idx >> 2, ko = (idx & 3) << 3;
      __builtin_amdgcn_global_load_lds(
          (__attribute__((address_space(1))) void*)(A + (size_t)(m0 + row) * K + k0 + ko),
          (__attribute__((address_space(3))) void*)(As + idx * 8), 16, 0, 0);
      __builtin_amdgcn_global_load_lds(
          (__attribute__((address_space(1))) void*)(Bw + (size_t)(n0 + row) * K + k0 + ko),
          (__attribute__((address_space(3))) void*)(Bs + idx * 8), 16, 0, 0);
    }
    asm volatile("s_waitcnt vmcnt(0)" ::: "memory");
    __syncthreads();  // staged data visible to all waves
    s16x8 af[4], bfr[4];
#pragma unroll
    for (int mi = 0; mi < 4; ++mi)
      af[mi] = *(const s16x8*)(As + (wr * 64 + mi * 16 + lo) * 32 + hi * 8);
#pragma unroll
    for (int ni = 0; ni < 4; ++ni)
      bfr[ni] = *(const s16x8*)(Bs + (wc * 64 + ni * 16 + lo) * 32 + hi * 8);
#pragma unroll
    for (int mi = 0; mi < 4; ++mi)
#pragma unroll
      for (int ni = 0; ni < 4; ++ni)
        acc[mi][ni] = __builtin_amdgcn_mfma_f32_16x16x32_bf16(af[mi], bfr[ni], acc[mi][ni], 0, 0, 0);
  }
  // epilogue: C/D layout col=lane&15, row=(lane>>4)*4+r
#pragma unroll
  for (int mi = 0; mi < 4; ++mi) {
#pragma unroll
    for (int ni = 0; ni < 4; ++ni) {
      int col = n0 + wc * 64 + ni * 16 + lo;
      int rowb = m0 + wr * 64 + mi * 16 + hi * 4;
#pragma unroll
      for (int r = 0; r < 4; ++r) {
        float v = acc[mi][ni][r];
        if (BF16OUT)
          ((unsigned short*)Cp)[(size_t)(rowb + r) * N + col] = f2bf(v);
        else
          ((float*)Cp)[(size_t)(rowb + r) * N + col] = v;
      }
    }
  }
}

// ---------------- RoPE + head-transpose: QKV[b,s,coloff+h*128+d] -> dst[b,h,s,d] ----------------
__global__ __launch_bounds__(256) void rope_kernel(const unsigned short* __restrict__ QKV,
                                                   const float* __restrict__ ctab,
                                                   const float* __restrict__ stab,
                                                   unsigned short* __restrict__ dst,
                                                   int nheads, int coloff, float scale) {
  int gid = blockIdx.x * 256 + threadIdx.x;
  int i = gid & 63;
  int rest = gid >> 6;
  int h = rest % nheads;
  int s = (rest / nheads) & (S_ - 1);
  int b = rest / (nheads * S_);
  const unsigned short* row = QKV + (size_t)(b * S_ + s) * NQKV + coloff + h * HD_;
  float x1 = bf2f(row[i]), x2 = bf2f(row[i + 64]);
  float c = ctab[s * 64 + i], sn = stab[s * 64 + i];
  unsigned short* drow = dst + ((size_t)(b * nheads + h) * S_ + s) * HD_;
  drow[i] = f2bf((x1 * c - x2 * sn) * scale);
  drow[i + 64] = f2bf((x1 * sn + x2 * c) * scale);
}

// ---------------- V transpose: QKV V-section -> Vt[b,kv,d,s] ----------------
__global__ __launch_bounds__(256) void vtrans_kernel(const unsigned short* __restrict__ QKV,
                                                     unsigned short* __restrict__ Vt) {
  int s0 = blockIdx.x * 64;
  int d0 = blockIdx.y * 64;
  int bk = blockIdx.z;  // b*4 + kvh
  int b = bk >> 2, kvh = bk & 3;
  __shared__ __align__(16) unsigned short tile[64][72];
  int tid = threadIdx.x;
  for (int e = tid; e < 512; e += 256) {
    int r = e >> 3, c = (e & 7) << 3;
    const unsigned short* src =
        QKV + (size_t)(b * S_ + s0 + r) * NQKV + 2560 + kvh * HD_ + d0 + c;
    *(uint4*)(&tile[r][c]) = *(const uint4*)src;
  }
  __syncthreads();
  for (int e = tid; e < 512; e += 256) {
    int d = e >> 3, sc = (e & 7) << 3;
    unsigned int wv[4];
#pragma unroll
    for (int j = 0; j < 4; ++j)
      wv[j] = (unsigned)tile[sc + 2 * j][d] | ((unsigned)tile[sc + 2 * j + 1][d] << 16);
    uint4 o = {wv[0], wv[1], wv[2], wv[3]};
    unsigned short* dstp = Vt + ((size_t)bk * HD_ + d0 + d) * S_ + s0 + sc;
    *(uint4*)dstp = o;
  }
}

// ---------------- flash attention: Q[b,h,s,d] (pre-scaled), K[b,kv,s,d], Vt[b,kv,d,s] ----------------
// block = 4 waves; wave handles 16 q-rows; KV tile = 64.
__global__ __launch_bounds__(256) void attn_kernel(const unsigned short* __restrict__ Qt,
                                                   const unsigned short* __restrict__ Kt,
                                                   const unsigned short* __restrict__ Vt,
                                                   const int* __restrict__ mask,
                                                   unsigned short* __restrict__ Out) {
  const int qt = blockIdx.x, h = blockIdx.y, b = blockIdx.z;
  const int kvh = h >> 2;
  const int tid = threadIdx.x, w = tid >> 6, l = tid & 63;
  const int lo = l & 15, hi = l >> 4;
  const int q0 = qt * 64 + w * 16;
  const unsigned short* Qb = Qt + ((size_t)(b * H_ + h) * S_ + q0) * HD_;
  const unsigned short* Kb = Kt + (size_t)(b * KVH_ + kvh) * S_ * HD_;
  const unsigned short* Vb = Vt + (size_t)(b * KVH_ + kvh) * HD_ * S_;
  const int* mb = mask + b * S_;
  __shared__ __align__(16) unsigned short P_lds[4][16 * 72];
  unsigned short* Pw = &P_lds[w][0];
  s16x8 qf[4];
#pragma unroll
  for (int c = 0; c < 4; ++c)
    qf[c] = *(const s16x8*)(Qb + lo * HD_ + c * 32 + hi * 8);
  f32x4 o[8] = {};
  float mrow[4], lrow[4];
#pragma unroll
  for (int r = 0; r < 4; ++r) { mrow[r] = -1e30f; lrow[r] = 0.f; }
  for (int t0 = 0; t0 < S_; t0 += 64) {
    f32x4 s[4];
#pragma unroll
    for (int sf = 0; sf < 4; ++sf) {
      f32x4 sv = {};
#pragma unroll
      for (int c = 0; c < 4; ++c) {
        s16x8 kf = *(const s16x8*)(Kb + (size_t)(t0 + sf * 16 + lo) * HD_ + c * 32 + hi * 8);
        sv = __builtin_amdgcn_mfma_f32_16x16x32_bf16(qf[c], kf, sv, 0, 0, 0);
      }
      if (mb[t0 + sf * 16 + lo]) {  // mask==true -> -inf (use -1e30; online softmax self-corrects)
#pragma unroll
        for (int r = 0; r < 4; ++r) sv[r] = -1e30f;
      }
      s[sf] = sv;
    }
    // per-row tile max (rows live in 16-lane groups, reg r = row (hi*4+r))
    float tm[4];
#pragma unroll
    for (int r = 0; r < 4; ++r)
      tm[r] = fmaxf(fmaxf(s[0][r], s[1][r]), fmaxf(s[2][r], s[3][r]));
#pragma unroll
    for (int d = 1; d < 16; d <<= 1)
#pragma unroll
      for (int r = 0; r < 4; ++r) tm[r] = fmaxf(tm[r], __shfl_xor(tm[r], d));
    float sc_[4];
#pragma unroll
    for (int r = 0; r < 4; ++r) {
      float mnew = fmaxf(mrow[r], tm[r]);
      sc_[r] = __expf(mrow[r] - mnew);
      mrow[r] = mnew;
    }
#pragma unroll
    for (int df = 0; df < 8; ++df)
#pragma unroll
      for (int r = 0; r < 4; ++r) o[df][r] *= sc_[r];
    float ts[4] = {0.f, 0.f, 0.f, 0.f};
#pragma unroll
    for (int sf = 0; sf < 4; ++sf)
#pragma unroll
      for (int r = 0; r < 4; ++r) {
        float p = __expf(s[sf][r] - mrow[r]);
        ts[r] += p;
        Pw[(hi * 4 + r) * 72 + sf * 16 + lo] = f2bf(p);  // C-layout -> LDS
      }
#pragma unroll
    for (int d = 1; d < 16; d <<= 1)
#pragma unroll
      for (int r = 0; r < 4; ++r) ts[r] += __shfl_xor(ts[r], d);
#pragma unroll
    for (int r = 0; r < 4; ++r) lrow[r] = lrow[r] * sc_[r] + ts[r];
    // reload P as A-layout frags (per-wave LDS; in-wave ds ordering suffices)
    s16x8 pa[2];
#pragma unroll
    for (int kk = 0; kk < 2; ++kk)
      pa[kk] = *(const s16x8*)(Pw + lo * 72 + kk * 32 + hi * 8);
#pragma unroll
    for (int df = 0; df < 8; ++df) {
#pragma unroll
      for (int kk = 0; kk < 2; ++kk) {
        s16x8 vf = *(const s16x8*)(Vb + (size_t)(df * 16 + lo) * S_ + t0 + kk * 32 + hi * 8);
        o[df] = __builtin_amdgcn_mfma_f32_16x16x32_bf16(pa[kk], vf, o[df], 0, 0, 0);
      }
    }
  }
  float inv[4];
#pragma unroll
  for (int r = 0; r < 4; ++r) inv[r] = 1.0f / lrow[r];
#pragma unroll
  for (int df = 0; df < 8; ++df)
#pragma unroll
    for (int r = 0; r < 4; ++r)
      Out[(size_t)(b * S_ + q0 + hi * 4 + r) * DIM_ + h * HD_ + df * 16 + lo] =
          f2bf(o[df][r] * inv[r]);
}

extern "C" void kernel_launch(void* const* d_in, const int* in_sizes, int n_in,
                              void* d_out, int out_size, void* d_ws, size_t ws_size,
                              hipStream_t stream) {
  (void)in_sizes; (void)n_in; (void)out_size; (void)ws_size;
  const float* x    = (const float*)d_in[0];
  const float* ctab = (const float*)d_in[1];
  const float* stab = (const float*)d_in[2];
  const int*   mask = (const int*)d_in[3];
  const float* Wq   = (const float*)d_in[4];
  const float* Wk   = (const float*)d_in[5];
  const float* Wv   = (const float*)d_in[6];
  const float* Wo   = (const float*)d_in[7];

  unsigned short* x_bf = (unsigned short*)d_ws;        // 8388608 elems (reused as attn_out)
  unsigned short* Wqkv = x_bf + 8388608;               // 6291456
  unsigned short* Wob  = Wqkv + 6291456;               // 4194304
  unsigned short* QKV  = Wob + 4194304;                // 12582912
  unsigned short* Qt   = QKV + 12582912;               // 8388608
  unsigned short* Kt   = Qt + 8388608;                 // 2097152
  unsigned short* Vt   = Kt + 2097152;                 // 2097152  (total ~88 MB)

  cast_f32_bf16<<<4096, 256, 0, stream>>>(x, x_bf, 8388608);
  cast_f32_bf16<<<2048, 256, 0, stream>>>(Wq, Wqkv, 4194304);
  cast_f32_bf16<<<512, 256, 0, stream>>>(Wk, Wqkv + 4194304, 1048576);
  cast_f32_bf16<<<512, 256, 0, stream>>>(Wv, Wqkv + 5242880, 1048576);
  cast_f32_bf16<<<2048, 256, 0, stream>>>(Wo, Wob, 4194304);

  gemm_bt<true><<<dim3(24, 32), 256, 0, stream>>>(x_bf, Wqkv, QKV, NQKV, DIM_);

  rope_kernel<<<16384, 256, 0, stream>>>(QKV, ctab, stab, Qt, H_, 0, 0.08838834764831845f);
  rope_kernel<<<4096, 256, 0, stream>>>(QKV, ctab, stab, Kt, KVH_, DIM_, 1.0f);
  vtrans_kernel<<<dim3(32, 2, 8), 256, 0, stream>>>(QKV, Vt);

  attn_kernel<<<dim3(32, 16, 2), 256, 0, stream>>>(Qt, Kt, Vt, mask, x_bf);

  gemm_bt<false><<<dim3(16, 32), 256, 0, stream>>>(x_bf, Wob, d_out, DIM_, DIM_);
}

// Round 2
// 407.034 us; speedup vs baseline: 1.7870x; 1.7870x over previous
//
#include <hip/hip_runtime.h>

typedef __attribute__((ext_vector_type(8))) short s16x8;
typedef __attribute__((ext_vector_type(4))) float f32x4;

#define B_    2
#define S_    2048
#define DIM_  2048
#define H_    16
#define KVH_  4
#define HD_   128
#define NQKV  3072

static __device__ __forceinline__ unsigned short f2bf(float f) {
  unsigned int u = __float_as_uint(f);
  u += 0x7fff + ((u >> 16) & 1);
  return (unsigned short)(u >> 16);
}
static __device__ __forceinline__ float bf2f(unsigned short h) {
  return __uint_as_float(((unsigned int)h) << 16);
}

// ---------------- cast f32 -> bf16 (vectorized) ----------------
__global__ __launch_bounds__(256) void cast_f32_bf16(const float* __restrict__ src,
                                                     unsigned short* __restrict__ dst, int n) {
  int i = (blockIdx.x * 256 + threadIdx.x) * 8;
  if (i >= n) return;
  float4 a = *(const float4*)(src + i);
  float4 b = *(const float4*)(src + i + 4);
  uint4 o;
  o.x = (unsigned)f2bf(a.x) | ((unsigned)f2bf(a.y) << 16);
  o.y = (unsigned)f2bf(a.z) | ((unsigned)f2bf(a.w) << 16);
  o.z = (unsigned)f2bf(b.x) | ((unsigned)f2bf(b.y) << 16);
  o.w = (unsigned)f2bf(b.z) | ((unsigned)f2bf(b.w) << 16);
  *(uint4*)(dst + i) = o;
}

// ---------------- m97-style GEMM: C[M,N] = A[M,K] * B[N,K]^T ----------------
template <bool BF16OUT>
__global__ __launch_bounds__(256) void gemm_bt(const unsigned short* __restrict__ A,
                                               const unsigned short* __restrict__ Bw,
                                               void* __restrict__ Cp, int N, int K) {
  __shared__ __align__(16) unsigned short As[128 * 32];
  __shared__ __align__(16) unsigned short Bs[128 * 32];
  const int tid = threadIdx.x;
  const int n0 = blockIdx.x * 128, m0 = blockIdx.y * 128;
  const int w = tid >> 6, l = tid & 63;
  const int wr = w >> 1, wc = w & 1;
  const int lo = l & 15, hi = l >> 4;
  f32x4 acc[4][4] = {};
  const int KT = K >> 5;
  for (int kt = 0; kt < KT; ++kt) {
    const int k0 = kt << 5;
    __syncthreads();
#pragma unroll
    for (int c = 0; c < 2; ++c) {
      int idx = tid + c * 256;
      int row = idx >> 2, ko = (idx & 3) << 3;
      __builtin_amdgcn_global_load_lds(
          (__attribute__((address_space(1))) void*)(A + (size_t)(m0 + row) * K + k0 + ko),
          (__attribute__((address_space(3))) void*)(As + idx * 8), 16, 0, 0);
      __builtin_amdgcn_global_load_lds(
          (__attribute__((address_space(1))) void*)(Bw + (size_t)(n0 + row) * K + k0 + ko),
          (__attribute__((address_space(3))) void*)(Bs + idx * 8), 16, 0, 0);
    }
    asm volatile("s_waitcnt vmcnt(0)" ::: "memory");
    __syncthreads();
    s16x8 af[4], bfr[4];
#pragma unroll
    for (int mi = 0; mi < 4; ++mi)
      af[mi] = *(const s16x8*)(As + (wr * 64 + mi * 16 + lo) * 32 + hi * 8);
#pragma unroll
    for (int ni = 0; ni < 4; ++ni)
      bfr[ni] = *(const s16x8*)(Bs + (wc * 64 + ni * 16 + lo) * 32 + hi * 8);
#pragma unroll
    for (int mi = 0; mi < 4; ++mi)
#pragma unroll
      for (int ni = 0; ni < 4; ++ni)
        acc[mi][ni] = __builtin_amdgcn_mfma_f32_16x16x32_bf16(af[mi], bfr[ni], acc[mi][ni], 0, 0, 0);
  }
#pragma unroll
  for (int mi = 0; mi < 4; ++mi) {
#pragma unroll
    for (int ni = 0; ni < 4; ++ni) {
      int col = n0 + wc * 64 + ni * 16 + lo;
      int rowb = m0 + wr * 64 + mi * 16 + hi * 4;
#pragma unroll
      for (int r = 0; r < 4; ++r) {
        float v = acc[mi][ni][r];
        if (BF16OUT)
          ((unsigned short*)Cp)[(size_t)(rowb + r) * N + col] = f2bf(v);
        else
          ((float*)Cp)[(size_t)(rowb + r) * N + col] = v;
      }
    }
  }
}

// ---------------- RoPE + head-transpose ----------------
__global__ __launch_bounds__(256) void rope_kernel(const unsigned short* __restrict__ QKV,
                                                   const float* __restrict__ ctab,
                                                   const float* __restrict__ stab,
                                                   unsigned short* __restrict__ dst,
                                                   int nheads, int coloff, float scale) {
  int gid = blockIdx.x * 256 + threadIdx.x;
  int i = gid & 63;
  int rest = gid >> 6;
  int h = rest % nheads;
  int s = (rest / nheads) & (S_ - 1);
  int b = rest / (nheads * S_);
  const unsigned short* row = QKV + (size_t)(b * S_ + s) * NQKV + coloff + h * HD_;
  float x1 = bf2f(row[i]), x2 = bf2f(row[i + 64]);
  float c = ctab[s * 64 + i], sn = stab[s * 64 + i];
  unsigned short* drow = dst + ((size_t)(b * nheads + h) * S_ + s) * HD_;
  drow[i] = f2bf((x1 * c - x2 * sn) * scale);
  drow[i + 64] = f2bf((x1 * sn + x2 * c) * scale);
}

// ---------------- V transpose: QKV V-section -> Vt[b,kv,d,s] ----------------
__global__ __launch_bounds__(256) void vtrans_kernel(const unsigned short* __restrict__ QKV,
                                                     unsigned short* __restrict__ Vt) {
  int s0 = blockIdx.x * 64;
  int d0 = blockIdx.y * 64;
  int bk = blockIdx.z;
  int b = bk >> 2, kvh = bk & 3;
  __shared__ __align__(16) unsigned short tile[64][72];
  int tid = threadIdx.x;
  for (int e = tid; e < 512; e += 256) {
    int r = e >> 3, c = (e & 7) << 3;
    const unsigned short* src =
        QKV + (size_t)(b * S_ + s0 + r) * NQKV + 2560 + kvh * HD_ + d0 + c;
    *(uint4*)(&tile[r][c]) = *(const uint4*)src;
  }
  __syncthreads();
  for (int e = tid; e < 512; e += 256) {
    int d = e >> 3, sc = (e & 7) << 3;
    unsigned int wv[4];
#pragma unroll
    for (int j = 0; j < 4; ++j)
      wv[j] = (unsigned)tile[sc + 2 * j][d] | ((unsigned)tile[sc + 2 * j + 1][d] << 16);
    uint4 o = {wv[0], wv[1], wv[2], wv[3]};
    unsigned short* dstp = Vt + ((size_t)bk * HD_ + d0 + d) * S_ + s0 + sc;
    *(uint4*)dstp = o;
  }
}

// ---------------- flash attention with LDS-staged K/V tiles ----------------
// 8 waves / 512 threads; wave handles 16 q-rows; block q-tile = 128; KV tile = 64.
// K tile [64 rows t][128 d] and Vt tile [128 rows d][64 t] staged via global_load_lds
// (linear LDS dest + inverse-XOR-swizzled global source; XOR on ds_read side).
__global__ __launch_bounds__(512) void attn_kernel(const unsigned short* __restrict__ Qt,
                                                   const unsigned short* __restrict__ Kt,
                                                   const unsigned short* __restrict__ Vt,
                                                   const int* __restrict__ mask,
                                                   unsigned short* __restrict__ Out) {
  const int qt = blockIdx.x, h = blockIdx.y, b = blockIdx.z;
  const int kvh = h >> 2;
  const int tid = threadIdx.x, w = tid >> 6, l = tid & 63;
  const int lo = l & 15, hi = l >> 4;
  const int q0 = qt * 128 + w * 16;
  const unsigned short* Qb = Qt + ((size_t)(b * H_ + h) * S_ + q0) * HD_;
  const unsigned short* Kb = Kt + (size_t)(b * KVH_ + kvh) * S_ * HD_;
  const unsigned short* Vb = Vt + (size_t)(b * KVH_ + kvh) * HD_ * S_;
  const int* mb = mask + b * S_;

  __shared__ __align__(16) unsigned short Ks[64 * 128];   // 16 KB, swizzled chunks
  __shared__ __align__(16) unsigned short Vs[128 * 64];   // 16 KB, swizzled chunks
  __shared__ float bias[S_];                               // 8 KB additive mask bias
  __shared__ __align__(16) unsigned short P_lds[8][16 * 72];
  unsigned short* Pw = &P_lds[w][0];

  for (int i = tid; i < S_; i += 512) bias[i] = mb[i] ? -1e30f : 0.0f;

  s16x8 qf[4];
#pragma unroll
  for (int c = 0; c < 4; ++c)
    qf[c] = *(const s16x8*)(Qb + lo * HD_ + c * 32 + hi * 8);
  f32x4 o[8] = {};
  float mrow[4], lrow[4];
#pragma unroll
  for (int r = 0; r < 4; ++r) { mrow[r] = -1e30f; lrow[r] = 0.f; }

  for (int t0 = 0; t0 < S_; t0 += 64) {
    __syncthreads();  // prev tile fully consumed (and bias ready on iter 0)
    // stage K: 64 rows x 16 chunks(8 elems). LDS linear; source chunk ^= row&7.
#pragma unroll
    for (int c = 0; c < 2; ++c) {
      int l4 = tid + c * 512;          // 0..1023
      int r = l4 >> 4, ch = l4 & 15;
      int chg = (ch & 8) | ((ch ^ r) & 7);
      __builtin_amdgcn_global_load_lds(
          (__attribute__((address_space(1))) void*)(Kb + (size_t)(t0 + r) * HD_ + chg * 8),
          (__attribute__((address_space(3))) void*)(Ks + l4 * 8), 16, 0, 0);
    }
    // stage Vt: 128 rows x 8 chunks(8 elems). source chunk ^= row&7.
#pragma unroll
    for (int c = 0; c < 2; ++c) {
      int l4 = tid + c * 512;
      int d = l4 >> 3, ch = l4 & 7;
      int chg = (ch ^ d) & 7;
      __builtin_amdgcn_global_load_lds(
          (__attribute__((address_space(1))) void*)(Vb + (size_t)d * S_ + t0 + chg * 8),
          (__attribute__((address_space(3))) void*)(Vs + l4 * 8), 16, 0, 0);
    }
    asm volatile("s_waitcnt vmcnt(0)" ::: "memory");
    __syncthreads();

    // QK^T from LDS
    f32x4 s[4];
#pragma unroll
    for (int sf = 0; sf < 4; ++sf) {
      f32x4 sv = {};
      int row = sf * 16 + lo;
#pragma unroll
      for (int c = 0; c < 4; ++c) {
        int ch = c * 4 + hi;
        int chs = (ch & 8) | ((ch ^ lo) & 7);
        s16x8 kf = *(const s16x8*)(Ks + row * 128 + chs * 8);
        sv = __builtin_amdgcn_mfma_f32_16x16x32_bf16(qf[c], kf, sv, 0, 0, 0);
      }
      float bv = bias[t0 + row];
#pragma unroll
      for (int r = 0; r < 4; ++r) sv[r] += bv;
      s[sf] = sv;
    }
    // online softmax (rows live in 16-lane groups; reg r = row hi*4+r)
    float tm[4];
#pragma unroll
    for (int r = 0; r < 4; ++r)
      tm[r] = fmaxf(fmaxf(s[0][r], s[1][r]), fmaxf(s[2][r], s[3][r]));
#pragma unroll
    for (int d = 1; d < 16; d <<= 1)
#pragma unroll
      for (int r = 0; r < 4; ++r) tm[r] = fmaxf(tm[r], __shfl_xor(tm[r], d));
    float sc_[4];
#pragma unroll
    for (int r = 0; r < 4; ++r) {
      float mnew = fmaxf(mrow[r], tm[r]);
      sc_[r] = __expf(mrow[r] - mnew);
      mrow[r] = mnew;
    }
#pragma unroll
    for (int df = 0; df < 8; ++df)
#pragma unroll
      for (int r = 0; r < 4; ++r) o[df][r] *= sc_[r];
    float ts[4] = {0.f, 0.f, 0.f, 0.f};
#pragma unroll
    for (int sf = 0; sf < 4; ++sf)
#pragma unroll
      for (int r = 0; r < 4; ++r) {
        float p = __expf(s[sf][r] - mrow[r]);
        ts[r] += p;
        Pw[(hi * 4 + r) * 72 + sf * 16 + lo] = f2bf(p);
      }
#pragma unroll
    for (int d = 1; d < 16; d <<= 1)
#pragma unroll
      for (int r = 0; r < 4; ++r) ts[r] += __shfl_xor(ts[r], d);
#pragma unroll
    for (int r = 0; r < 4; ++r) lrow[r] = lrow[r] * sc_[r] + ts[r];
    // P: C-layout -> A-layout via per-wave LDS
    s16x8 pa[2];
#pragma unroll
    for (int kk = 0; kk < 2; ++kk)
      pa[kk] = *(const s16x8*)(Pw + lo * 72 + kk * 32 + hi * 8);
    // PV from LDS (swizzled Vt tile)
#pragma unroll
    for (int df = 0; df < 8; ++df) {
      int d = df * 16 + lo;
#pragma unroll
      for (int kk = 0; kk < 2; ++kk) {
        int ch = kk * 4 + hi;
        int chs = (ch ^ lo) & 7;
        s16x8 vf = *(const s16x8*)(Vs + d * 64 + chs * 8);
        o[df] = __builtin_amdgcn_mfma_f32_16x16x32_bf16(pa[kk], vf, o[df], 0, 0, 0);
      }
    }
  }
  float inv[4];
#pragma unroll
  for (int r = 0; r < 4; ++r) inv[r] = 1.0f / lrow[r];
#pragma unroll
  for (int df = 0; df < 8; ++df)
#pragma unroll
    for (int r = 0; r < 4; ++r)
      Out[(size_t)(b * S_ + q0 + hi * 4 + r) * DIM_ + h * HD_ + df * 16 + lo] =
          f2bf(o[df][r] * inv[r]);
}

extern "C" void kernel_launch(void* const* d_in, const int* in_sizes, int n_in,
                              void* d_out, int out_size, void* d_ws, size_t ws_size,
                              hipStream_t stream) {
  (void)in_sizes; (void)n_in; (void)out_size; (void)ws_size;
  const float* x    = (const float*)d_in[0];
  const float* ctab = (const float*)d_in[1];
  const float* stab = (const float*)d_in[2];
  const int*   mask = (const int*)d_in[3];
  const float* Wq   = (const float*)d_in[4];
  const float* Wk   = (const float*)d_in[5];
  const float* Wv   = (const float*)d_in[6];
  const float* Wo   = (const float*)d_in[7];

  unsigned short* x_bf = (unsigned short*)d_ws;        // 8388608 elems (reused as attn_out)
  unsigned short* Wqkv = x_bf + 8388608;               // 6291456
  unsigned short* Wob  = Wqkv + 6291456;               // 4194304
  unsigned short* QKV  = Wob + 4194304;                // 12582912
  unsigned short* Qt   = QKV + 12582912;               // 8388608
  unsigned short* Kt   = Qt + 8388608;                 // 2097152
  unsigned short* Vt   = Kt + 2097152;                 // 2097152

  cast_f32_bf16<<<4096, 256, 0, stream>>>(x, x_bf, 8388608);
  cast_f32_bf16<<<2048, 256, 0, stream>>>(Wq, Wqkv, 4194304);
  cast_f32_bf16<<<512, 256, 0, stream>>>(Wk, Wqkv + 4194304, 1048576);
  cast_f32_bf16<<<512, 256, 0, stream>>>(Wv, Wqkv + 5242880, 1048576);
  cast_f32_bf16<<<2048, 256, 0, stream>>>(Wo, Wob, 4194304);

  gemm_bt<true><<<dim3(24, 32), 256, 0, stream>>>(x_bf, Wqkv, QKV, NQKV, DIM_);

  rope_kernel<<<16384, 256, 0, stream>>>(QKV, ctab, stab, Qt, H_, 0, 0.08838834764831845f);
  rope_kernel<<<4096, 256, 0, stream>>>(QKV, ctab, stab, Kt, KVH_, DIM_, 1.0f);
  vtrans_kernel<<<dim3(32, 2, 8), 256, 0, stream>>>(QKV, Vt);

  attn_kernel<<<dim3(16, 16, 2), 512, 0, stream>>>(Qt, Kt, Vt, mask, x_bf);

  gemm_bt<false><<<dim3(16, 32), 256, 0, stream>>>(x_bf, Wob, d_out, DIM_, DIM_);
}